// Round 9
// baseline (499.824 us; speedup 1.0000x reference)
//
#include <hip/hip_runtime.h>
#include <hip/hip_bf16.h>

#define N_NODES  100000
#define N_EDGES  1600000
#define D_FEAT   128
#define HIDDEN   128
#define N_CLASSES 10
#define NUM_GRAPHS 64

#define NBUCK 250        // dst buckets
#define NPB   400        // nodes per bucket (250*400 = 100000 exactly)
#define CHUNK 12500      // edges per block in passes A/C (128*12500 = 1.6M exactly)
#define GT    128        // nodes per GEMM tile
#define NPAD  100096     // N_NODES padded to GT multiple (782*128)
#define NTILES (NPAD / GT)   // 782
#define TPB   3          // tiles per GEMM block
#define GEMM_GRID ((NTILES + TPB - 1) / TPB)   // 261

typedef __bf16 bf16x8 __attribute__((ext_vector_type(8)));
typedef float  f32x4  __attribute__((ext_vector_type(4)));

static __device__ __forceinline__ unsigned short f2bf(float f) {
    __bf16 b = (__bf16)f;
    return __builtin_bit_cast(unsigned short, b);
}

// async global->LDS, 16B per lane. LDS dest must be wave-uniform base + lane*16.
static __device__ __forceinline__ void async_copy16(void* lds, const void* g) {
    __builtin_amdgcn_global_load_lds(
        (const __attribute__((address_space(1))) void*)g,
        (__attribute__((address_space(3))) void*)lds, 16, 0, 0);
}

// ---------------------------------------------------------------------------
// Convert all 6 fp32 weight matrices to bf16 in one launch.
// ---------------------------------------------------------------------------
__global__ void conv_w6_kernel(const float* __restrict__ W0, const float* __restrict__ W1,
                               const float* __restrict__ W2, const float* __restrict__ W3,
                               const float* __restrict__ W4, const float* __restrict__ W5,
                               __bf16* __restrict__ out) {
    const float* Ws[6] = {W0, W1, W2, W3, W4, W5};
    int m = blockIdx.x >> 6;
    int i = (blockIdx.x & 63) * 256 + threadIdx.x;
    out[m * (HIDDEN * D_FEAT) + i] = (__bf16)Ws[m][i];
}

// ---------------------------------------------------------------------------
// x (fp32) -> bf16, 8 elems per thread.
// ---------------------------------------------------------------------------
__global__ __launch_bounds__(256) void xconv_kernel(const float* __restrict__ x,
                                                    __bf16* __restrict__ out) {
    int i = blockIdx.x * 256 + threadIdx.x;
    float4 v0 = ((const float4*)x)[i * 2];
    float4 v1 = ((const float4*)x)[i * 2 + 1];
    bf16x8 o;
    o[0] = (__bf16)v0.x; o[1] = (__bf16)v0.y; o[2] = (__bf16)v0.z; o[3] = (__bf16)v0.w;
    o[4] = (__bf16)v1.x; o[5] = (__bf16)v1.y; o[6] = (__bf16)v1.z; o[7] = (__bf16)v1.w;
    ((bf16x8*)out)[i] = o;
}

// ---------------------------------------------------------------------------
// Pass A: bucket histogram via LDS
// ---------------------------------------------------------------------------
__global__ __launch_bounds__(256) void bucket_hist_kernel(const int* __restrict__ ei,
                                                          int* __restrict__ bh) {
    __shared__ int h[NBUCK];
    int t = threadIdx.x;
    for (int i = t; i < NBUCK; i += 256) h[i] = 0;
    __syncthreads();
    int e0 = blockIdx.x * CHUNK;
    for (int e = e0 + t; e < e0 + CHUNK; e += 256) {
        int d = ei[N_EDGES + e];
        atomicAdd(&h[d / NPB], 1);
    }
    __syncthreads();
    for (int i = t; i < NBUCK; i += 256) atomicAdd(&bh[i], h[i]);
}

// ---------------------------------------------------------------------------
// Pass B: single-block exclusive scan of bucket counts -> bases + cursors
// ---------------------------------------------------------------------------
__global__ __launch_bounds__(256) void bucket_scan_kernel(const int* __restrict__ bh,
                                                          int* __restrict__ bbase,
                                                          int* __restrict__ bcur) {
    __shared__ int tmp[256];
    int t = threadIdx.x;
    int v = (t < NBUCK) ? bh[t] : 0;
    tmp[t] = v;
    __syncthreads();
    for (int off = 1; off < 256; off <<= 1) {
        int x = (t >= off) ? tmp[t - off] : 0;
        __syncthreads();
        tmp[t] += x;
        __syncthreads();
    }
    if (t < NBUCK) { int e = tmp[t] - v; bbase[t] = e; bcur[t] = e; }
    if (t == NBUCK - 1) bbase[NBUCK] = tmp[t];
}

// ---------------------------------------------------------------------------
// Pass C: partition edges into bucket-major int2{src,dst}.
// ---------------------------------------------------------------------------
__global__ __launch_bounds__(256) void bucket_scatter_kernel(const int* __restrict__ ei,
                                                             int* __restrict__ bcur,
                                                             int2* __restrict__ bkt) {
    __shared__ int h[NBUCK];
    __shared__ int lbase[NBUCK];
    int t = threadIdx.x;
    for (int i = t; i < NBUCK; i += 256) h[i] = 0;
    __syncthreads();
    int e0 = blockIdx.x * CHUNK;
    for (int e = e0 + t; e < e0 + CHUNK; e += 256) {
        int d = ei[N_EDGES + e];
        atomicAdd(&h[d / NPB], 1);
    }
    __syncthreads();
    for (int i = t; i < NBUCK; i += 256) {
        lbase[i] = atomicAdd(&bcur[i], h[i]);
        h[i] = 0;
    }
    __syncthreads();
    for (int e = e0 + t; e < e0 + CHUNK; e += 256) {
        int s = ei[e];
        int d = ei[N_EDGES + e];
        int bb = d / NPB;
        int pos = lbase[bb] + atomicAdd(&h[bb], 1);
        bkt[pos] = make_int2(s, d);
    }
}

// ---------------------------------------------------------------------------
// Pass D: one block per bucket -> rp + csr_src (dense writes)
// ---------------------------------------------------------------------------
__global__ __launch_bounds__(256) void bucket_csr_kernel(const int2* __restrict__ bkt,
                                                         const int* __restrict__ bbase,
                                                         int* __restrict__ rp,
                                                         int* __restrict__ csr_src) {
    const int b = blockIdx.x;
    const int n0 = b * NPB;
    const int ebase = bbase[b], eend = bbase[b + 1];
    __shared__ int cnt[NPB];
    __shared__ int part[128];
    __shared__ int excl[NPB];
    int t = threadIdx.x;
    for (int i = t; i < NPB; i += 256) cnt[i] = 0;
    __syncthreads();
    for (int e = ebase + t; e < eend; e += 256) {
        int2 p = bkt[e];
        atomicAdd(&cnt[p.y - n0], 1);
    }
    __syncthreads();
    int gs = 0;
    if (t < 100) { gs = cnt[4 * t] + cnt[4 * t + 1] + cnt[4 * t + 2] + cnt[4 * t + 3]; part[t] = gs; }
    else if (t < 128) part[t] = 0;
    __syncthreads();
    for (int off = 1; off < 128; off <<= 1) {
        int x = 0;
        if (t < 128 && t >= off) x = part[t - off];
        __syncthreads();
        if (t < 128) part[t] += x;
        __syncthreads();
    }
    if (t < 100) part[t] -= gs;
    __syncthreads();
    for (int i = t; i < NPB; i += 256) {
        int g = i >> 2;
        int e0 = part[g];
        for (int j = g * 4; j < i; j++) e0 += cnt[j];
        excl[i] = e0;
    }
    __syncthreads();
    for (int i = t; i < NPB; i += 256) {
        rp[n0 + i] = ebase + excl[i];
        cnt[i] = excl[i];
    }
    if (b == NBUCK - 1 && t == 0) rp[N_NODES] = N_EDGES;
    __syncthreads();
    for (int e = ebase + t; e < eend; e += 256) {
        int2 p = bkt[e];
        int pos = ebase + atomicAdd(&cnt[p.y - n0], 1);
        csr_src[pos] = p.x;
    }
}

// ---------------------------------------------------------------------------
// Dual GEMM, persistent + double-buffered LDS:
// Block handles TPB consecutive 128-node tiles. Fill(t+1) is issued AFTER the
// barrier that drains fill(t) -> barrier never waits on the just-issued fill,
// so staging of tile t+1 overlaps compute+store of tile t. W register-resident
// across all tiles. XOR-swizzled LDS columns (fill-order compatible).
// MFMA: A=W rows, B=h rows => D: col=node, row=feat (4 consecutive per lane).
// ---------------------------------------------------------------------------
__global__ __launch_bounds__(256) void dual_gemm_kernel(
    const __bf16* __restrict__ h,
    const __bf16* __restrict__ Wl, const __bf16* __restrict__ Wr,
    const float* __restrict__ bias,
    __bf16* __restrict__ out_l, __bf16* __restrict__ out_r, int M)
{
    __shared__ __bf16 tile_lds[2][GT * 128];   // 2 x 32 KB

    const int tid  = threadIdx.x;
    const int wave = tid >> 6;
    const int lane = tid & 63;
    const int kq = lane >> 4;
    const int ln = lane & 15;
    const int f_base = wave * 32;
    const int tile0 = blockIdx.x * TPB;

    auto fill = [&](int tile, int buf) {
        const __bf16* hsrc = h + (size_t)tile * GT * 128;
        #pragma unroll
        for (int i = 0; i < 8; i++) {
            int u = i * 256 + tid;
            int row = u >> 4;
            int sc = (u & 15) ^ (row & 15);
            async_copy16(&tile_lds[buf][u * 8], hsrc + row * 128 + sc * 8);
        }
    };

    if (tile0 < NTILES) fill(tile0, 0);

    // W fragments resident for the whole block (overlap with first fill)
    bf16x8 wfrag[2][2][4];
    #pragma unroll
    for (int t = 0; t < 2; t++) {
        int wrow = f_base + t * 16 + ln;
        #pragma unroll
        for (int kc = 0; kc < 4; kc++) {
            int k0 = kc * 32 + kq * 8;
            wfrag[0][t][kc] = *(const bf16x8*)(Wl + wrow * 128 + k0);
            wfrag[1][t][kc] = *(const bf16x8*)(Wr + wrow * 128 + k0);
        }
    }
    float4 bias4[2];
    bias4[0] = *(const float4*)(bias + f_base + kq * 4);
    bias4[1] = *(const float4*)(bias + f_base + 16 + kq * 4);

    #pragma unroll 1
    for (int s = 0; s < TPB; s++) {
        int tile = tile0 + s;
        if (tile >= NTILES) break;

        __syncthreads();                       // drains fill(tile) [+ prior stores]
        if (s + 1 < TPB && tile + 1 < NTILES)  // issue next fill AFTER the drain
            fill(tile + 1, (s + 1) & 1);

        const __bf16* lds = tile_lds[s & 1];
        const int node_base = tile * GT;

        #pragma unroll 2
        for (int tau = 0; tau < GT / 16; tau++) {
            int r = tau * 16 + ln;
            bf16x8 hfrag[4];
            #pragma unroll
            for (int kc = 0; kc < 4; kc++) {
                int c = (4 * kc + kq) ^ ln;
                hfrag[kc] = *(const bf16x8*)&lds[r * 128 + c * 8];
            }

            f32x4 accl[2] = {(f32x4)(0.f), (f32x4)(0.f)};
            f32x4 accr[2] = {(f32x4)(0.f), (f32x4)(0.f)};
            #pragma unroll
            for (int kc = 0; kc < 4; kc++) {
                #pragma unroll
                for (int t = 0; t < 2; t++) {
                    accl[t] = __builtin_amdgcn_mfma_f32_16x16x32_bf16(wfrag[0][t][kc], hfrag[kc], accl[t], 0, 0, 0);
                    accr[t] = __builtin_amdgcn_mfma_f32_16x16x32_bf16(wfrag[1][t][kc], hfrag[kc], accr[t], 0, 0, 0);
                }
            }

            int node = node_base + tau * 16 + ln;
            if (node < M) {
                size_t rowoff = (size_t)node * 128;
                #pragma unroll
                for (int t = 0; t < 2; t++) {
                    int fc = f_base + t * 16 + kq * 4;
                    ushort4 ol;
                    ol.x = f2bf(accl[t][0]); ol.y = f2bf(accl[t][1]);
                    ol.z = f2bf(accl[t][2]); ol.w = f2bf(accl[t][3]);
                    *(ushort4*)(out_l + rowoff + fc) = ol;
                    ushort4 orr;
                    orr.x = f2bf(accr[t][0] + bias4[t].x);
                    orr.y = f2bf(accr[t][1] + bias4[t].y);
                    orr.z = f2bf(accr[t][2] + bias4[t].z);
                    orr.w = f2bf(accr[t][3] + bias4[t].w);
                    *(ushort4*)(out_r + rowoff + fc) = orr;
                }
            }
        }
    }
}

// ---------------------------------------------------------------------------
// CSR gather-aggregate, wave-per-node: 4 edge-slots x 16 feat-lanes.
// Zero intra-wave imbalance (all lanes same node); slot partials combined
// with 2 shfl_xor levels. out[n] = (relu?)(base[n] + sum_j hl[csr_src[j]])
// ---------------------------------------------------------------------------
template<bool RELU>
__global__ __launch_bounds__(256) void gather_kernel(
    const __bf16* __restrict__ hl, const int* __restrict__ rp,
    const int* __restrict__ csr_src, const __bf16* __restrict__ base,
    __bf16* __restrict__ outp, int N)
{
    int wave = threadIdx.x >> 6;
    int lane = threadIdx.x & 63;
    int nid = blockIdx.x * 4 + wave;
    if (nid >= N) return;
    int es = lane >> 4;          // edge slot 0..3
    int f8 = lane & 15;          // 8 feats per lane
    int start = rp[nid], end = rp[nid + 1];

    float a[8] = {0.f, 0.f, 0.f, 0.f, 0.f, 0.f, 0.f, 0.f};

    int j = start + es;
    for (; j + 4 < end; j += 8) {
        int s0 = csr_src[j];
        int s1 = csr_src[j + 4];
        bf16x8 u0 = ((const bf16x8*)hl)[(size_t)s0 * 16 + f8];
        bf16x8 u1 = ((const bf16x8*)hl)[(size_t)s1 * 16 + f8];
        #pragma unroll
        for (int i = 0; i < 8; i++) a[i] += (float)u0[i] + (float)u1[i];
    }
    if (j < end) {
        int s0 = csr_src[j];
        bf16x8 u0 = ((const bf16x8*)hl)[(size_t)s0 * 16 + f8];
        #pragma unroll
        for (int i = 0; i < 8; i++) a[i] += (float)u0[i];
    }

    // combine the 4 slots (lane^16 flips slot bit0, lane^32 flips slot bit1)
    #pragma unroll
    for (int i = 0; i < 8; i++) {
        a[i] += __shfl_xor(a[i], 16, 64);
        a[i] += __shfl_xor(a[i], 32, 64);
    }

    if (es == 0) {
        bf16x8 b8 = ((const bf16x8*)base)[(size_t)nid * 16 + f8];
        bf16x8 o;
        #pragma unroll
        for (int i = 0; i < 8; i++) {
            float v = a[i] + (float)b8[i];
            if (RELU) v = fmaxf(v, 0.f);
            o[i] = (__bf16)v;
        }
        ((bf16x8*)outp)[(size_t)nid * 16 + f8] = o;
    }
}

// ---------------------------------------------------------------------------
// Pool: pooled[batch[n]] += h[n] (bf16 in, fp32 acc/out). batch sorted.
// ---------------------------------------------------------------------------
__global__ __launch_bounds__(256) void pool_kernel(
    const __bf16* __restrict__ h, const int* __restrict__ batch,
    float* __restrict__ pooled, int N)
{
    int idx = blockIdx.x * 256 + threadIdx.x;
    int f = idx & 127;
    int chunk = idx >> 7;
    int n0 = chunk * 32;
    if (n0 >= N) return;
    int n1 = n0 + 32; if (n1 > N) n1 = N;
    int curb = batch[n0];
    float acc = 0.f;
    for (int n = n0; n < n1; n++) {
        int b = batch[n];
        if (b != curb) {
            unsafeAtomicAdd(&pooled[(size_t)curb * 128 + f], acc);
            acc = 0.f; curb = b;
        }
        acc += (float)h[(size_t)n * 128 + f];
    }
    unsafeAtomicAdd(&pooled[(size_t)curb * 128 + f], acc);
}

__global__ void final_gemm_kernel(
    const float* __restrict__ pooled, const float* __restrict__ Wout,
    const float* __restrict__ bout, float* __restrict__ out)
{
    int idx = blockIdx.x * 64 + threadIdx.x;
    if (idx < NUM_GRAPHS * N_CLASSES) {
        int g = idx / N_CLASSES;
        int c = idx % N_CLASSES;
        float acc = bout[c];
        for (int k = 0; k < HIDDEN; k++)
            acc += pooled[g * HIDDEN + k] * Wout[c * HIDDEN + k];
        out[idx] = acc;
    }
}

extern "C" void kernel_launch(void* const* d_in, const int* in_sizes, int n_in,
                              void* d_out, int out_size, void* d_ws, size_t ws_size,
                              hipStream_t stream) {
    const float* x     = (const float*)d_in[0];
    const int*   ei    = (const int*)d_in[1];
    const int*   batch = (const int*)d_in[2];
    const float* W1l = (const float*)d_in[3];
    const float* b1  = (const float*)d_in[4];
    const float* W1r = (const float*)d_in[5];
    const float* W2l = (const float*)d_in[6];
    const float* b2  = (const float*)d_in[7];
    const float* W2r = (const float*)d_in[8];
    const float* W3l = (const float*)d_in[9];
    const float* b3  = (const float*)d_in[10];
    const float* W3r = (const float*)d_in[11];
    const float* Wout = (const float*)d_in[12];
    const float* bout = (const float*)d_in[13];
    float* out = (float*)d_out;

    char* ws = (char*)d_ws;
    size_t off = 0;
    __bf16* bufL  = (__bf16*)(ws + off); off += (size_t)N_NODES * 128 * sizeof(__bf16);
    __bf16* bufR  = (__bf16*)(ws + off); off += (size_t)N_NODES * 128 * sizeof(__bf16);
    __bf16* bufH  = (__bf16*)(ws + off); off += (size_t)NPAD * 128 * sizeof(__bf16); // padded (GEMM input)
    float* pooled = (float*)(ws + off);  off += (size_t)NUM_GRAPHS * HIDDEN * sizeof(float);
    __bf16* wbf   = (__bf16*)(ws + off); off += 6 * (size_t)HIDDEN * D_FEAT * sizeof(__bf16);
    int* rp       = (int*)(ws + off);    off += ((size_t)N_NODES + 16) * sizeof(int);
    int* csr_src  = (int*)(ws + off);    off += (size_t)N_EDGES * sizeof(int);
    int2* bkt     = (int2*)(ws + off);   off += (size_t)N_EDGES * sizeof(int2);
    int* bh       = (int*)(ws + off);    off += (NBUCK + 8) * sizeof(int);
    int* bbase    = (int*)(ws + off);    off += (NBUCK + 8) * sizeof(int);
    int* bcur     = (int*)(ws + off);    off += (NBUCK + 8) * sizeof(int);

    const int WSZ = HIDDEN * D_FEAT;

    conv_w6_kernel<<<6 * 64, 256, 0, stream>>>(W1l, W1r, W2l, W2r, W3l, W3r, wbf);
    xconv_kernel<<<N_NODES * 128 / (256 * 8), 256, 0, stream>>>(x, bufH);

    // Bucket-based CSR build (all-dense writes)
    hipMemsetAsync(bh, 0, NBUCK * sizeof(int), stream);
    bucket_hist_kernel<<<128, 256, 0, stream>>>(ei, bh);
    bucket_scan_kernel<<<1, 256, 0, stream>>>(bh, bbase, bcur);
    bucket_scatter_kernel<<<128, 256, 0, stream>>>(ei, bcur, bkt);
    bucket_csr_kernel<<<NBUCK, 256, 0, stream>>>(bkt, bbase, rp, csr_src);

    const int gath_grid = (N_NODES + 3) / 4;

    // Layer 1 (input = bf16-converted x in bufH; gather overwrites bufH after)
    dual_gemm_kernel<<<GEMM_GRID, 256, 0, stream>>>(bufH, wbf + 0 * WSZ, wbf + 1 * WSZ, b1, bufL, bufR, N_NODES);
    gather_kernel<true><<<gath_grid, 256, 0, stream>>>(bufL, rp, csr_src, bufR, bufH, N_NODES);

    // Layer 2
    dual_gemm_kernel<<<GEMM_GRID, 256, 0, stream>>>(bufH, wbf + 2 * WSZ, wbf + 3 * WSZ, b2, bufL, bufR, N_NODES);
    gather_kernel<true><<<gath_grid, 256, 0, stream>>>(bufL, rp, csr_src, bufR, bufH, N_NODES);

    // Layer 3 (no relu)
    dual_gemm_kernel<<<GEMM_GRID, 256, 0, stream>>>(bufH, wbf + 4 * WSZ, wbf + 5 * WSZ, b3, bufL, bufR, N_NODES);
    gather_kernel<false><<<gath_grid, 256, 0, stream>>>(bufL, rp, csr_src, bufR, bufH, N_NODES);

    // Pool + final
    hipMemsetAsync(pooled, 0, (size_t)NUM_GRAPHS * HIDDEN * sizeof(float), stream);
    const int pool_grid = ((N_NODES + 31) / 32 * 128 + 255) / 256;
    pool_kernel<<<pool_grid, 256, 0, stream>>>(bufH, batch, pooled, N_NODES);
    final_gemm_kernel<<<10, 64, 0, stream>>>(pooled, Wout, bout, out);
}

// Round 10
// 439.661 us; speedup vs baseline: 1.1368x; 1.1368x over previous
//
#include <hip/hip_runtime.h>
#include <hip/hip_bf16.h>

#define N_NODES  100000
#define N_EDGES  1600000
#define D_FEAT   128
#define HIDDEN   128
#define N_CLASSES 10
#define NUM_GRAPHS 64

#define NBUCK 250        // dst buckets
#define NPB   400        // nodes per bucket (250*400 = 100000)
#define BCAP  7168       // per-bucket edge capacity (mean 6400 + 9.6 sigma)
#define GT    64         // nodes per GEMM tile
#define NPAD  100096     // N_NODES padded to GT multiple
#define NTILES (NPAD / GT)   // 1564

typedef __bf16 bf16x8 __attribute__((ext_vector_type(8)));
typedef float  f32x4  __attribute__((ext_vector_type(4)));

static __device__ __forceinline__ unsigned short f2bf(float f) {
    __bf16 b = (__bf16)f;
    return __builtin_bit_cast(unsigned short, b);
}

// async global->LDS, 16B per lane. LDS dest = wave-uniform base + lane*16.
static __device__ __forceinline__ void async_copy16(void* lds, const void* g) {
    __builtin_amdgcn_global_load_lds(
        (const __attribute__((address_space(1))) void*)g,
        (__attribute__((address_space(3))) void*)lds, 16, 0, 0);
}

// ---------------------------------------------------------------------------
// Convert all 6 fp32 weight matrices to bf16 in one launch.
// ---------------------------------------------------------------------------
__global__ void conv_w6_kernel(const float* __restrict__ W0, const float* __restrict__ W1,
                               const float* __restrict__ W2, const float* __restrict__ W3,
                               const float* __restrict__ W4, const float* __restrict__ W5,
                               __bf16* __restrict__ out) {
    const float* Ws[6] = {W0, W1, W2, W3, W4, W5};
    int m = blockIdx.x >> 6;
    int i = (blockIdx.x & 63) * 256 + threadIdx.x;
    out[m * (HIDDEN * D_FEAT) + i] = (__bf16)Ws[m][i];
}

// ---------------------------------------------------------------------------
// x (fp32) -> bf16, 8 elems/thread; zero-fills the NPAD padding rows.
// grid covers NPAD*128 elems.
// ---------------------------------------------------------------------------
__global__ __launch_bounds__(256) void xconv_kernel(const float* __restrict__ x,
                                                    __bf16* __restrict__ out) {
    int i = blockIdx.x * 256 + threadIdx.x;
    bf16x8 o;
    if (i < N_NODES * 128 / 8) {
        float4 v0 = ((const float4*)x)[i * 2];
        float4 v1 = ((const float4*)x)[i * 2 + 1];
        o[0] = (__bf16)v0.x; o[1] = (__bf16)v0.y; o[2] = (__bf16)v0.z; o[3] = (__bf16)v0.w;
        o[4] = (__bf16)v1.x; o[5] = (__bf16)v1.y; o[6] = (__bf16)v1.z; o[7] = (__bf16)v1.w;
    } else {
        #pragma unroll
        for (int k = 0; k < 8; k++) o[k] = (__bf16)0.f;
    }
    if (i < NPAD * 128 / 8) ((bf16x8*)out)[i] = o;
}

// ---------------------------------------------------------------------------
// Pass S: partition edges into bucket-major int2{src,dst} regions of size
// BCAP (no global hist/scan needed: per-block LDS hist -> wholesale claim on
// a zero-initialized global cursor -> dense chunk writes).
// ---------------------------------------------------------------------------
__global__ __launch_bounds__(256) void bucket_scatter_kernel(const int* __restrict__ ei,
                                                             int* __restrict__ gcur,
                                                             int2* __restrict__ bkt) {
    __shared__ int h[NBUCK];
    __shared__ int lb[NBUCK];
    int t = threadIdx.x;
    const int CH = N_EDGES / 256;   // 6250
    for (int i = t; i < NBUCK; i += 256) h[i] = 0;
    __syncthreads();
    int e0 = blockIdx.x * CH;
    for (int e = e0 + t; e < e0 + CH; e += 256) {
        int d = ei[N_EDGES + e];
        atomicAdd(&h[d / NPB], 1);
    }
    __syncthreads();
    for (int i = t; i < NBUCK; i += 256) {
        lb[i] = atomicAdd(&gcur[i], h[i]);
        h[i] = 0;
    }
    __syncthreads();
    for (int e = e0 + t; e < e0 + CH; e += 256) {
        int s = ei[e];
        int d = ei[N_EDGES + e];
        int bb = d / NPB;
        int pos = lb[bb] + atomicAdd(&h[bb], 1);
        if (pos < BCAP) bkt[(size_t)bb * BCAP + pos] = make_int2(s, d);
    }
}

// ---------------------------------------------------------------------------
// Pass D: one block per bucket -> rpse{start,end} + csr_src (bucket-major,
// dense writes within the bucket's BCAP window).
// ---------------------------------------------------------------------------
__global__ __launch_bounds__(256) void bucket_csr_kernel(const int2* __restrict__ bkt,
                                                         const int* __restrict__ gcur,
                                                         int2* __restrict__ rpse,
                                                         int* __restrict__ csr_src) {
    const int b = blockIdx.x;
    const int n0 = b * NPB;
    const int base = b * BCAP;
    int m = gcur[b]; if (m > BCAP) m = BCAP;
    __shared__ int cnt[NPB];
    __shared__ int part[128];
    __shared__ int excl[NPB];
    int t = threadIdx.x;
    for (int i = t; i < NPB; i += 256) cnt[i] = 0;
    __syncthreads();
    for (int e = t; e < m; e += 256) {
        int2 p = bkt[base + e];
        atomicAdd(&cnt[p.y - n0], 1);
    }
    __syncthreads();
    int gs = 0;
    if (t < 100) { gs = cnt[4 * t] + cnt[4 * t + 1] + cnt[4 * t + 2] + cnt[4 * t + 3]; part[t] = gs; }
    else if (t < 128) part[t] = 0;
    __syncthreads();
    for (int off = 1; off < 128; off <<= 1) {
        int x = 0;
        if (t < 128 && t >= off) x = part[t - off];
        __syncthreads();
        if (t < 128) part[t] += x;
        __syncthreads();
    }
    if (t < 100) part[t] -= gs;
    __syncthreads();
    for (int i = t; i < NPB; i += 256) {
        int g = i >> 2;
        int e0 = part[g];
        for (int j = g * 4; j < i; j++) e0 += cnt[j];
        excl[i] = e0;
    }
    __syncthreads();
    for (int i = t; i < NPB; i += 256) {
        rpse[n0 + i] = make_int2(base + excl[i], base + excl[i] + cnt[i]);
    }
    __syncthreads();
    for (int i = t; i < NPB; i += 256) cnt[i] = excl[i];   // reuse as cursor
    __syncthreads();
    for (int e = t; e < m; e += 256) {
        int2 p = bkt[base + e];
        int pos = base + atomicAdd(&cnt[p.y - n0], 1);
        csr_src[pos] = p.x;
    }
}

// ---------------------------------------------------------------------------
// Pure gather-aggregate: agg[n] = sum_j h[csr_src[j]]   (no base, no relu)
// 16 lanes per node (bf16x8 per lane), 4 nodes/wave, j-loop unrolled x4.
// ---------------------------------------------------------------------------
__global__ __launch_bounds__(256) void gather_kernel(
    const __bf16* __restrict__ h, const int2* __restrict__ rpse,
    const int* __restrict__ csr_src, __bf16* __restrict__ agg, int N)
{
    int nid = blockIdx.x * 16 + (threadIdx.x >> 4);
    if (nid >= N) return;
    int f8 = threadIdx.x & 15;
    int2 se = rpse[nid];

    float a[8] = {0.f, 0.f, 0.f, 0.f, 0.f, 0.f, 0.f, 0.f};

    int j = se.x;
    for (; j + 3 < se.y; j += 4) {
        int s0 = csr_src[j];
        int s1 = csr_src[j + 1];
        int s2 = csr_src[j + 2];
        int s3 = csr_src[j + 3];
        bf16x8 u0 = ((const bf16x8*)h)[(size_t)s0 * 16 + f8];
        bf16x8 u1 = ((const bf16x8*)h)[(size_t)s1 * 16 + f8];
        bf16x8 u2 = ((const bf16x8*)h)[(size_t)s2 * 16 + f8];
        bf16x8 u3 = ((const bf16x8*)h)[(size_t)s3 * 16 + f8];
        #pragma unroll
        for (int i = 0; i < 8; i++)
            a[i] += ((float)u0[i] + (float)u1[i]) + ((float)u2[i] + (float)u3[i]);
    }
    for (; j < se.y; j++) {
        int s0 = csr_src[j];
        bf16x8 u0 = ((const bf16x8*)h)[(size_t)s0 * 16 + f8];
        #pragma unroll
        for (int i = 0; i < 8; i++) a[i] += (float)u0[i];
    }
    bf16x8 o;
    #pragma unroll
    for (int i = 0; i < 8; i++) o[i] = (__bf16)a[i];
    ((bf16x8*)agg)[(size_t)nid * 16 + f8] = o;
}

// ---------------------------------------------------------------------------
// Fused dual-input GEMM: out = (relu?)(agg@Wl.T + h@Wr.T + b)   (bf16 out)
// One block = one 64-node tile (2x16KB LDS via global_load_lds, XOR-swizzled),
// ~4 blocks/CU co-resident for cross-block latency hiding. W register-
// resident. MFMA: A=W rows, B=h/agg rows => D: col=node, row=feat.
// ---------------------------------------------------------------------------
template<bool RELU>
__global__ __launch_bounds__(256) void fused_gemm_kernel(
    const __bf16* __restrict__ hA,      // self features [NPAD,128]
    const __bf16* __restrict__ hG,      // aggregated features [NPAD,128]
    const __bf16* __restrict__ Wl, const __bf16* __restrict__ Wr,
    const float* __restrict__ bias,
    __bf16* __restrict__ outp, int M)
{
    __shared__ __bf16 lds[2][GT * 128];   // [0]=agg, [1]=self; 16 KB each

    const int tid  = threadIdx.x;
    const int wave = tid >> 6;
    const int lane = tid & 63;
    const int kq = lane >> 4;
    const int ln = lane & 15;
    const int node_base = blockIdx.x * GT;
    const int f_base = wave * 32;

    // fills: 1024 16B units per tile; unit u: row=u>>4, col16=(u&15)^(row&15)
    {
        const __bf16* gsrc = hG + (size_t)node_base * 128;
        const __bf16* asrc = hA + (size_t)node_base * 128;
        #pragma unroll
        for (int i = 0; i < 4; i++) {
            int u = i * 256 + tid;
            int row = u >> 4;
            int sc = (u & 15) ^ (row & 15);
            async_copy16(&lds[0][u * 8], gsrc + row * 128 + sc * 8);
            async_copy16(&lds[1][u * 8], asrc + row * 128 + sc * 8);
        }
    }

    // W fragments resident (loads overlap the fills; barrier drains both)
    bf16x8 wfragL[2][4], wfragR[2][4];
    #pragma unroll
    for (int t = 0; t < 2; t++) {
        int wrow = f_base + t * 16 + ln;
        #pragma unroll
        for (int kc = 0; kc < 4; kc++) {
            int k0 = kc * 32 + kq * 8;
            wfragL[t][kc] = *(const bf16x8*)(Wl + wrow * 128 + k0);
            wfragR[t][kc] = *(const bf16x8*)(Wr + wrow * 128 + k0);
        }
    }
    float4 bias4[2];
    bias4[0] = *(const float4*)(bias + f_base + kq * 4);
    bias4[1] = *(const float4*)(bias + f_base + 16 + kq * 4);

    __syncthreads();

    #pragma unroll 2
    for (int tau = 0; tau < GT / 16; tau++) {
        int r = tau * 16 + ln;
        bf16x8 gfrag[4], afrag[4];
        #pragma unroll
        for (int kc = 0; kc < 4; kc++) {
            int c = (4 * kc + kq) ^ ln;
            gfrag[kc] = *(const bf16x8*)&lds[0][r * 128 + c * 8];
            afrag[kc] = *(const bf16x8*)&lds[1][r * 128 + c * 8];
        }

        f32x4 acc[2] = {(f32x4)(0.f), (f32x4)(0.f)};
        #pragma unroll
        for (int kc = 0; kc < 4; kc++) {
            #pragma unroll
            for (int t = 0; t < 2; t++) {
                acc[t] = __builtin_amdgcn_mfma_f32_16x16x32_bf16(wfragL[t][kc], gfrag[kc], acc[t], 0, 0, 0);
                acc[t] = __builtin_amdgcn_mfma_f32_16x16x32_bf16(wfragR[t][kc], afrag[kc], acc[t], 0, 0, 0);
            }
        }

        int node = node_base + tau * 16 + ln;
        if (node < M) {
            size_t rowoff = (size_t)node * 128;
            #pragma unroll
            for (int t = 0; t < 2; t++) {
                int fc = f_base + t * 16 + kq * 4;
                ushort4 o;
                float v0 = acc[t][0] + bias4[t].x;
                float v1 = acc[t][1] + bias4[t].y;
                float v2 = acc[t][2] + bias4[t].z;
                float v3 = acc[t][3] + bias4[t].w;
                if (RELU) {
                    v0 = fmaxf(v0, 0.f); v1 = fmaxf(v1, 0.f);
                    v2 = fmaxf(v2, 0.f); v3 = fmaxf(v3, 0.f);
                }
                o.x = f2bf(v0); o.y = f2bf(v1); o.z = f2bf(v2); o.w = f2bf(v3);
                *(ushort4*)(outp + rowoff + fc) = o;
            }
        }
    }
}

// ---------------------------------------------------------------------------
// Pool: pooled[batch[n]] += h[n] (bf16 in, fp32 acc/out). batch sorted.
// ---------------------------------------------------------------------------
__global__ __launch_bounds__(256) void pool_kernel(
    const __bf16* __restrict__ h, const int* __restrict__ batch,
    float* __restrict__ pooled, int N)
{
    int idx = blockIdx.x * 256 + threadIdx.x;
    int f = idx & 127;
    int chunk = idx >> 7;
    int n0 = chunk * 32;
    if (n0 >= N) return;
    int n1 = n0 + 32; if (n1 > N) n1 = N;
    int curb = batch[n0];
    float acc = 0.f;
    for (int n = n0; n < n1; n++) {
        int b = batch[n];
        if (b != curb) {
            unsafeAtomicAdd(&pooled[(size_t)curb * 128 + f], acc);
            acc = 0.f; curb = b;
        }
        acc += (float)h[(size_t)n * 128 + f];
    }
    unsafeAtomicAdd(&pooled[(size_t)curb * 128 + f], acc);
}

__global__ void final_gemm_kernel(
    const float* __restrict__ pooled, const float* __restrict__ Wout,
    const float* __restrict__ bout, float* __restrict__ out)
{
    int idx = blockIdx.x * 64 + threadIdx.x;
    if (idx < NUM_GRAPHS * N_CLASSES) {
        int g = idx / N_CLASSES;
        int c = idx % N_CLASSES;
        float acc = bout[c];
        for (int k = 0; k < HIDDEN; k++)
            acc += pooled[g * HIDDEN + k] * Wout[c * HIDDEN + k];
        out[idx] = acc;
    }
}

extern "C" void kernel_launch(void* const* d_in, const int* in_sizes, int n_in,
                              void* d_out, int out_size, void* d_ws, size_t ws_size,
                              hipStream_t stream) {
    const float* x     = (const float*)d_in[0];
    const int*   ei    = (const int*)d_in[1];
    const int*   batch = (const int*)d_in[2];
    const float* W1l = (const float*)d_in[3];
    const float* b1  = (const float*)d_in[4];
    const float* W1r = (const float*)d_in[5];
    const float* W2l = (const float*)d_in[6];
    const float* b2  = (const float*)d_in[7];
    const float* W2r = (const float*)d_in[8];
    const float* W3l = (const float*)d_in[9];
    const float* b3  = (const float*)d_in[10];
    const float* W3r = (const float*)d_in[11];
    const float* Wout = (const float*)d_in[12];
    const float* bout = (const float*)d_in[13];
    float* out = (float*)d_out;

    char* ws = (char*)d_ws;
    size_t off = 0;
    const size_t NB = (size_t)NPAD * 128 * sizeof(__bf16);   // 25.6 MB
    __bf16* B0    = (__bf16*)(ws + off); off += NB;   // xbf, later h2-out
    __bf16* B1    = (__bf16*)(ws + off); off += NB;   // agg (all layers)
    __bf16* B2    = (__bf16*)(ws + off); off += NB;   // h1-out, h3-out
    float* pooled = (float*)(ws + off);  off += (size_t)NUM_GRAPHS * HIDDEN * sizeof(float);
    __bf16* wbf   = (__bf16*)(ws + off); off += 6 * (size_t)HIDDEN * D_FEAT * sizeof(__bf16);
    int2* rpse    = (int2*)(ws + off);   off += (size_t)N_NODES * sizeof(int2);
    int* csr_src  = (int*)(ws + off);    off += (size_t)NBUCK * BCAP * sizeof(int);   // 7.2 MB
    int2* bkt     = (int2*)(ws + off);   off += (size_t)NBUCK * BCAP * sizeof(int2);  // 14.3 MB
    int* gcur     = (int*)(ws + off);    off += (NBUCK + 8) * sizeof(int);

    const int WSZ = HIDDEN * D_FEAT;

    conv_w6_kernel<<<6 * 64, 256, 0, stream>>>(W1l, W1r, W2l, W2r, W3l, W3r, wbf);
    xconv_kernel<<<NPAD * 128 / (256 * 8), 256, 0, stream>>>(x, B0);

    // 2-pass capacity-based CSR build (all-dense writes, no hist/scan)
    hipMemsetAsync(gcur, 0, NBUCK * sizeof(int), stream);
    bucket_scatter_kernel<<<256, 256, 0, stream>>>(ei, gcur, bkt);
    bucket_csr_kernel<<<NBUCK, 256, 0, stream>>>(bkt, gcur, rpse, csr_src);

    const int gath_grid = (N_NODES + 15) / 16;

    // Layer 1: agg1 = gather(xbf); h1 = relu(agg1@W1l.T + xbf@W1r.T + b1)
    gather_kernel<<<gath_grid, 256, 0, stream>>>(B0, rpse, csr_src, B1, N_NODES);
    fused_gemm_kernel<true><<<NTILES, 256, 0, stream>>>(B0, B1, wbf + 0 * WSZ, wbf + 1 * WSZ, b1, B2, N_NODES);

    // Layer 2
    gather_kernel<<<gath_grid, 256, 0, stream>>>(B2, rpse, csr_src, B1, N_NODES);
    fused_gemm_kernel<true><<<NTILES, 256, 0, stream>>>(B2, B1, wbf + 2 * WSZ, wbf + 3 * WSZ, b2, B0, N_NODES);

    // Layer 3 (no relu)
    gather_kernel<<<gath_grid, 256, 0, stream>>>(B0, rpse, csr_src, B1, N_NODES);
    fused_gemm_kernel<false><<<NTILES, 256, 0, stream>>>(B0, B1, wbf + 4 * WSZ, wbf + 5 * WSZ, b3, B2, N_NODES);

    // Pool + final
    hipMemsetAsync(pooled, 0, (size_t)NUM_GRAPHS * HIDDEN * sizeof(float), stream);
    const int pool_grid = ((N_NODES + 31) / 32 * 128 + 255) / 256;
    pool_kernel<<<pool_grid, 256, 0, stream>>>(B2, batch, pooled, N_NODES);
    final_gemm_kernel<<<10, 64, 0, stream>>>(pooled, Wout, bout, out);
}